// Round 4
// baseline (948.090 us; speedup 1.0000x reference)
//
#include <hip/hip_runtime.h>
#include <hip/hip_bf16.h>
#include <stdint.h>

// Shapes: B=4, N=512, IN=1024, H=256 (MID=512), 4H=1024, OUT_K=50, N_POS=30, SE=64
// out[4][50][512][512] fp32.

typedef float  floatx4 __attribute__((ext_vector_type(4)));
typedef short  short4v __attribute__((ext_vector_type(4)));
typedef short  short8  __attribute__((ext_vector_type(8)));
typedef int    int4v   __attribute__((ext_vector_type(4)));

#define LOG2E_F  1.4426950408889634f
#define TWOLOG2E_F 2.8853900817779268f

__device__ __forceinline__ short f2bf(float f) {
    __hip_bfloat16 h = __float2bfloat16(f);
    return *reinterpret_cast<short*>(&h);
}
__device__ __forceinline__ float fexp2(float x) {
#if __has_builtin(__builtin_amdgcn_exp2f)
    return __builtin_amdgcn_exp2f(x);
#else
    float r; asm("v_exp_f32 %0, %1" : "=v"(r) : "v"(x)); return r;
#endif
}
__device__ __forceinline__ float frcp(float x) {
#if __has_builtin(__builtin_amdgcn_rcpf)
    return __builtin_amdgcn_rcpf(x);
#else
    float r; asm("v_rcp_f32 %0, %1" : "=v"(r) : "v"(x)); return r;
#endif
}
__device__ __forceinline__ int q8i(float x) {
    int q = (int)rintf(x);
    return q > 127 ? 127 : (q < -127 ? -127 : q);
}

// ---------------------------------------------------------------------------
// prep: ssize[50][32] = Ws @ emb^T ; sbias[128]; biasc1[2048]; biasc2[1024];
// bf16 pre-conversions:
//   abf   [2048][1024] = input_embeds            (aliases ht region)
//   wihbf [2048][1024] = [Wih_f ; Wih_b]
//   wc2bf [1024][512]  = [W_head ; W_tail]       (aliases sarr region)
//   wcbf  [128][512]   = [Wh;0;Wt;0] rows of W
// ---------------------------------------------------------------------------
__global__ __launch_bounds__(256) void prep_k(
    const float* __restrict__ input_embeds,
    const float* __restrict__ Wih_f, const float* __restrict__ Wih_b,
    const float* __restrict__ W_head, const float* __restrict__ W_tail,
    const float* __restrict__ W, const float* __restrict__ emb,
    const float* __restrict__ bih_f, const float* __restrict__ bhh_f,
    const float* __restrict__ bih_b, const float* __restrict__ bhh_b,
    const float* __restrict__ b_head, const float* __restrict__ b_tail,
    float* __restrict__ ssize, float* __restrict__ sbias,
    float* __restrict__ biasc1, float* __restrict__ biasc2,
    __hip_bfloat16* __restrict__ abf, __hip_bfloat16* __restrict__ wihbf,
    __hip_bfloat16* __restrict__ wc2bf, __hip_bfloat16* __restrict__ wcbf)
{
    const int g0 = blockIdx.x * 256 + threadIdx.x;
    const int gs = gridDim.x * 256;

    for (int i4 = g0; i4 < (2048 * 1024) / 4; i4 += gs) {
        floatx4 v = *(const floatx4*)(input_embeds + (size_t)i4 * 4);
        short4v s = { f2bf(v[0]), f2bf(v[1]), f2bf(v[2]), f2bf(v[3]) };
        *(short4v*)(abf + (size_t)i4 * 4) = s;
    }
    for (int i4 = g0; i4 < (2048 * 1024) / 4; i4 += gs) {
        int r = i4 >> 8, c4 = (i4 & 255) * 4;
        const float* src = (r < 1024) ? (Wih_f + (size_t)r * 1024 + c4)
                                      : (Wih_b + (size_t)(r - 1024) * 1024 + c4);
        floatx4 v = *(const floatx4*)src;
        short4v s = { f2bf(v[0]), f2bf(v[1]), f2bf(v[2]), f2bf(v[3]) };
        *(short4v*)(wihbf + (size_t)i4 * 4) = s;
    }
    for (int i4 = g0; i4 < (1024 * 512) / 4; i4 += gs) {
        int r = i4 >> 7, c4 = (i4 & 127) * 4;
        const float* src = (r < 512) ? (W_head + (size_t)r * 512 + c4)
                                     : (W_tail + (size_t)(r - 512) * 512 + c4);
        floatx4 v = *(const floatx4*)src;
        short4v s = { f2bf(v[0]), f2bf(v[1]), f2bf(v[2]), f2bf(v[3]) };
        *(short4v*)(wc2bf + (size_t)i4 * 4) = s;
    }
    for (int i4 = g0; i4 < (128 * 512) / 4; i4 += gs) {
        int r = i4 >> 7, c4 = (i4 & 127) * 4;
        short4v s = {0, 0, 0, 0};
        if (r < 50) {
            const float* p = W + (size_t)r * 1090 + c4;
            s[0] = f2bf(p[0]); s[1] = f2bf(p[1]); s[2] = f2bf(p[2]); s[3] = f2bf(p[3]);
        } else if (r >= 64 && r < 114) {
            const float* p = W + (size_t)(r - 64) * 1090 + 513 + c4;
            s[0] = f2bf(p[0]); s[1] = f2bf(p[1]); s[2] = f2bf(p[2]); s[3] = f2bf(p[3]);
        }
        *(short4v*)(wcbf + (size_t)i4 * 4) = s;
    }

    for (int i = g0; i < 1600; i += gs) {          // ssize [50][32], cols 30,31 = 0
        int k = i >> 5, pp = i & 31;
        float acc = 0.0f;
        if (pp < 30)
            for (int h = 0; h < 64; ++h)
                acc += W[(size_t)k * 1090 + 1026 + h] * emb[pp * 64 + h];
        ssize[i] = acc;
    }
    for (int i = g0; i < 128; i += gs) {
        float v = 0.0f;
        if (i < 50)                    v = W[(size_t)i * 1090 + 512];
        else if (i >= 64 && i < 114)   v = W[(size_t)(i - 64) * 1090 + 1025];
        sbias[i] = v;
    }
    for (int i = g0; i < 2048; i += gs)
        biasc1[i] = (i < 1024) ? (bih_f[i] + bhh_f[i]) : (bih_b[i - 1024] + bhh_b[i - 1024]);
    for (int i = g0; i < 1024; i += gs)
        biasc2[i] = (i < 512) ? b_head[i] : b_tail[i - 512];
}

// ---------------------------------------------------------------------------
// gemm_bt: C[m][n] = sum_k A[m][k] * B[n][k] + bias[n]; A,B bf16.
// Block tile 128x64, 4 waves each 32 (M) x 64 (N). BK=32. MFMA 16x16x32 bf16.
// mode 0: fp32 store into xg[d][t][b][gate][unit] (contiguous 64B runs per
//         quad -> coalesced), PRE-SCALED per gate: i,f,o -> -log2e ; g -> +2log2e
// mode 1: leaky_relu -> bf16 store, row stride 1024    (GEMM2)
// mode 2: TRANSPOSED fp32 store sarrT[n][m], ld 2048   (GEMM3)
// ---------------------------------------------------------------------------
__global__ __launch_bounds__(256) void gemm_bt(
    const __hip_bfloat16* __restrict__ Abf, int lda,
    int a_split_n, int a_split_off,
    const __hip_bfloat16* __restrict__ Bbf, int ldb,
    const float* __restrict__ bias, int K, int mode,
    float* __restrict__ out0, __hip_bfloat16* __restrict__ out1)
{
    __shared__ __align__(16) short As[128][48];   // stride 48 el = 96 B (conflict pad)
    __shared__ __align__(16) short Bs[64][48];
    const int tid   = threadIdx.x;
    const int nbase = blockIdx.x * 64;
    const int mbase = blockIdx.y * 128;
    const int aoff  = (nbase >= a_split_n) ? a_split_off : 0;
    const int arow = tid >> 1, akq = (tid & 1) * 16;   // A: 128 rows x 32k, 16 el/thread
    const int brow = tid >> 2, bkq = (tid & 3) * 8;    // B: 64 rows x 32k, 8 el/thread
    const int wv = tid >> 6, ln = tid & 63, l15 = ln & 15, quad = ln >> 4;

    floatx4 acc[2][4];
#pragma unroll
    for (int i = 0; i < 2; ++i)
#pragma unroll
        for (int j = 0; j < 4; ++j) acc[i][j] = (floatx4){0.f, 0.f, 0.f, 0.f};

    const unsigned short* A = (const unsigned short*)Abf;
    const unsigned short* B = (const unsigned short*)Bbf;
    const int KI = K >> 5;
    for (int kk = 0; kk < KI; ++kk) {
        const unsigned short* pa = A + (size_t)(mbase + arow) * lda + aoff + kk * 32 + akq;
        short8 sa0 = *(const short8*)pa;
        short8 sa1 = *(const short8*)(pa + 8);
        const unsigned short* pb = B + (size_t)(nbase + brow) * ldb + kk * 32 + bkq;
        short8 sb = *(const short8*)pb;

        __syncthreads();   // previous iter's MFMA reads done
        *(short8*)&As[arow][akq]     = sa0;
        *(short8*)&As[arow][akq + 8] = sa1;
        *(short8*)&Bs[brow][bkq]     = sb;
        __syncthreads();   // staging visible

        short8 a0 = *(const short8*)&As[wv * 32 + l15][quad * 8];
        short8 a1 = *(const short8*)&As[wv * 32 + 16 + l15][quad * 8];
#pragma unroll
        for (int nt = 0; nt < 4; ++nt) {
            short8 bb = *(const short8*)&Bs[nt * 16 + l15][quad * 8];
            acc[0][nt] = __builtin_amdgcn_mfma_f32_16x16x32_bf16(a0, bb, acc[0][nt], 0, 0, 0);
            acc[1][nt] = __builtin_amdgcn_mfma_f32_16x16x32_bf16(a1, bb, acc[1][nt], 0, 0, 0);
        }
    }

#pragma unroll
    for (int mt = 0; mt < 2; ++mt)
#pragma unroll
        for (int nt = 0; nt < 4; ++nt) {
            const int gc = nbase + nt * 16 + l15;
            const float bv = bias[gc];
#pragma unroll
            for (int r = 0; r < 4; ++r) {
                const int gr = mbase + wv * 32 + mt * 16 + quad * 4 + r;
                float v = acc[mt][nt][r] + bv;
                if (mode == 0) {
                    // xg[d][t][b][g][u]: 16 lanes of a quad write 64B contiguous
                    const int d = gc >> 10, nn = gc & 1023;
                    const int g = nn >> 8, u = nn & 255;
                    const int t = gr & 511, b = gr >> 9;
                    const float gsc = (g == 2) ? TWOLOG2E_F : -LOG2E_F;
                    out0[((((size_t)d * 512 + t) * 4 + b) * 4 + g) * 256 + u] = v * gsc;
                } else if (mode == 1) {
                    v = v < 0.0f ? 0.01f * v : v;
                    out1[(size_t)gr * 1024 + gc] = __float2bfloat16(v);
                } else {
                    out0[(size_t)gc * 2048 + gr] = v;   // sarrT[n][m]
                }
            }
        }
}

// ---------------------------------------------------------------------------
// lstm_k: 2 blocks (fwd/bwd) x 1024 threads. Whh quantized to per-row i8,
// register-resident A-frags; per-step mfma_i32_16x16x64_i8 (M=1024,N=16,K=256).
// R4: hq compacted to [2][4][16][16] (only the 16 real (ksub,batch) B-slots);
// bb ds_reads predicated to the 16 real lanes (l15<4), other 48 lanes carry
// constant-zero registers -> per-step broadcast LDS traffic 64KB -> 16KB.
// xg layout now [d][t][b][gate][unit]: 4 scalar prefetch loads per step.
// Hot-loop barrier stays lgkmcnt-only (global store + prefetch in flight).
// ---------------------------------------------------------------------------
__global__ __launch_bounds__(1024) void lstm_k(
    const float* __restrict__ Whh_f, const float* __restrict__ Whh_b,
    const float* __restrict__ xg, __hip_bfloat16* __restrict__ hcat)
{
    const int dir = blockIdx.x;
    const float* Whh = dir ? Whh_b : Whh_f;
    const float* xgd = xg + (size_t)dir * 512 * 4 * 1024;
    __shared__ __align__(16) float sm_lds[1024];
    __shared__ __align__(16) signed char hq[2][4][16][16];  // [parity][kf][ksub*4+b][16 i8]
    __shared__ __align__(16) int gexch[16][64][4];          // per-wave repack buffer
    const int tid = threadIdx.x;
    const int wv = tid >> 6, ln = tid & 63, l15 = ln & 15, quad = ln >> 4;

    // pass 1: per-vrow max|Whh| (wave-per-row, coalesced)
    for (int v = wv * 64; v < wv * 64 + 64; ++v) {
        const int orig = ((v & 3) << 8) | (v >> 2);   // gate*256 + unit
        floatx4 x = *(const floatx4*)(Whh + (size_t)orig * 256 + ln * 4);
        float m = fmaxf(fmaxf(fabsf(x[0]), fabsf(x[1])), fmaxf(fabsf(x[2]), fabsf(x[3])));
#pragma unroll
        for (int off = 32; off; off >>= 1) m = fmaxf(m, __shfl_xor(m, off, 64));
        if (ln == 0) sm_lds[v] = m;
    }
    for (int i = tid; i < 2 * 4 * 16 * 16 / 4; i += 1024) ((int*)hq)[i] = 0;
    __syncthreads();

    // pass 2: quantize Whh into register A-frags (4 M-tiles x 4 K-frags per wave)
    int4v afrag[4][4];
#pragma unroll
    for (int tt = 0; tt < 4; ++tt) {
        const int vrow = (wv * 4 + tt) * 16 + l15;
        const int orig = ((vrow & 3) << 8) | (vrow >> 2);
        const float sm = sm_lds[vrow];
        const float inv = sm > 1e-30f ? 127.0f / sm : 0.0f;
#pragma unroll
        for (int kf = 0; kf < 4; ++kf) {
            const float* p = Whh + (size_t)orig * 256 + kf * 64 + quad * 16;
            int4v fr;
#pragma unroll
            for (int j = 0; j < 4; ++j) {
                floatx4 w4 = *(const floatx4*)(p + j * 4);
                int b0 = q8i(w4[0] * inv), b1 = q8i(w4[1] * inv);
                int b2 = q8i(w4[2] * inv), b3 = q8i(w4[3] * inv);
                fr[j] = (b0 & 255) | ((b1 & 255) << 8) | ((b2 & 255) << 16) | (b3 << 24);
            }
            afrag[tt][kf] = fr;
        }
    }

    // static per-lane gate-set assignment: unit u_mine, batch (all 64 lanes used)
    const int u_mine = wv * 16 + (ln >> 2);
    const int batch  = ln & 3;
    floatx4 scl;
    {
        const float sc = 1.0f / 16129.0f;   // 1/127^2
        floatx4 s4 = *(const floatx4*)&sm_lds[u_mine * 4];
        scl[0] = s4[0] * (sc * -LOG2E_F);
        scl[1] = s4[1] * (sc * -LOG2E_F);
        scl[2] = s4[2] * (sc *  TWOLOG2E_F);
        scl[3] = s4[3] * (sc * -LOG2E_F);
    }
    // hq write slot: kf = u>>6, slot = ((u>>4)&3)*4 + batch, byte = u&15
    signed char* hq_w = &hq[0][u_mine >> 6][(((u_mine >> 4) & 3) << 2) + batch][u_mine & 15];
    // bb read slot for active lanes (l15<4): (ln>>4)*4 + l15
    const int bslot = (ln >> 4) * 4 + l15;
    const int t0 = dir ? 511 : 0;
    const ptrdiff_t xstep = dir ? -4096 : 4096;    // floats per t-step
    const ptrdiff_t hstep = dir ? -512 : 512;      // bf16 elements per t-step
    const float* xp = xgd + (size_t)batch * 1024 + u_mine + (size_t)t0 * 4096;
    __hip_bfloat16* hc_p = hcat + (size_t)batch * 512 * 512 + dir * 256 + u_mine
                                + (size_t)t0 * 512;

    float c = 0.0f;
    const int4v z4 = {0, 0, 0, 0};   // persistent C=0 operand for kf=0 MFMA
    __syncthreads();

    floatx4 xga, xgb;
    xga[0] = xp[0]; xga[1] = xp[256]; xga[2] = xp[512]; xga[3] = xp[768];

    // One sub-step. P = parity read this step (write P^1). XC = this step's xg
    // regs, XN = regs filled with the prefetch. Trailing barrier drains LDS
    // only (lgkmcnt): hcat global store + xg prefetch stay in flight.
#define LSTM_STEP(P, XC, XN)                                                    \
    {                                                                           \
        xp += xstep;                                                            \
        XN[0] = xp[0]; XN[1] = xp[256]; XN[2] = xp[512]; XN[3] = xp[768];       \
        int4v bb0 = z4, bb1 = z4, bb2 = z4, bb3 = z4;                           \
        if (l15 < 4) {                                                          \
            bb0 = *(const int4v*)&hq[P][0][bslot][0];                           \
            bb1 = *(const int4v*)&hq[P][1][bslot][0];                           \
            bb2 = *(const int4v*)&hq[P][2][bslot][0];                           \
            bb3 = *(const int4v*)&hq[P][3][bslot][0];                           \
        }                                                                       \
        int4v acc[4];                                                           \
        _Pragma("unroll")                                                       \
        for (int tt = 0; tt < 4; ++tt) {                                        \
            int4v t0v = __builtin_amdgcn_mfma_i32_16x16x64_i8(                  \
                afrag[tt][0], bb0, z4, 0, 0, 0);                                \
            t0v = __builtin_amdgcn_mfma_i32_16x16x64_i8(                        \
                afrag[tt][1], bb1, t0v, 0, 0, 0);                               \
            t0v = __builtin_amdgcn_mfma_i32_16x16x64_i8(                        \
                afrag[tt][2], bb2, t0v, 0, 0, 0);                               \
            acc[tt] = __builtin_amdgcn_mfma_i32_16x16x64_i8(                    \
                afrag[tt][3], bb3, t0v, 0, 0, 0);                               \
        }                                                                       \
        if (l15 < 4) {                                                          \
            _Pragma("unroll")                                                   \
            for (int tt = 0; tt < 4; ++tt)                                      \
                *(int4v*)&gexch[wv][(tt * 4 + quad) * 4 + l15][0] = acc[tt];    \
        }                                                                       \
        int4v g = *(const int4v*)&gexch[wv][ln][0];                             \
        float gi = fmaf((float)g[0], scl[0], XC[0]);                            \
        float gf = fmaf((float)g[1], scl[1], XC[1]);                            \
        float gg = fmaf((float)g[2], scl[2], XC[2]);                            \
        float go = fmaf((float)g[3], scl[3], XC[3]);                            \
        float iv = frcp(1.0f + fexp2(gi));           /* sigmoid (pre * -log2e) */\
        float fv = frcp(1.0f + fexp2(gf));                                      \
        float tg = fmaf(-2.0f, frcp(1.0f + fexp2(gg)), 1.0f); /* tanh */        \
        float ov = frcp(1.0f + fexp2(go));                                      \
        c = fmaf(fv, c, iv * tg);                                               \
        float tc = fmaf(-2.0f, frcp(1.0f + fexp2(c * TWOLOG2E_F)), 1.0f);       \
        float h = ov * tc;                                                      \
        *hc_p = __float2bfloat16(h);                                            \
        hq_w[(P) ? 0 : 1024] = (signed char)(int)rintf(h * 127.0f); /* |h|<1 */ \
        hc_p += hstep;                                                          \
        asm volatile("s_waitcnt lgkmcnt(0)" ::: "memory");                      \
        __builtin_amdgcn_s_barrier();                                           \
        __builtin_amdgcn_sched_barrier(0);                                      \
        asm volatile("" ::: "memory");                                          \
    }

    for (int s = 0; s < 512; s += 2) {
        LSTM_STEP(0, xga, xgb)
        LSTM_STEP(1, xgb, xga)
    }
#undef LSTM_STEP
}

// ---------------------------------------------------------------------------
// final: out[b][k][m][n] = s_head[b,m,k] + s_tail[b,n,k] + S[k][clamp(n-m)]
// sarrT is transposed: sarrT[col 0..127][m 0..2047] -> contiguous loads here.
// ---------------------------------------------------------------------------
__global__ __launch_bounds__(256) void final_k(
    const float* __restrict__ sarrT, const float* __restrict__ ssize,
    float* __restrict__ out)
{
    const int mb = blockIdx.x * 64;
    const int k  = blockIdx.y;
    const int b  = blockIdx.z;
    __shared__ float st[512];
    __shared__ float sh[64];
    __shared__ float ss[32];
    const int tid = threadIdx.x;
    for (int n = tid; n < 512; n += 256)
        st[n] = sarrT[(size_t)(64 + k) * 2048 + b * 512 + n];
    if (tid < 64) sh[tid] = sarrT[(size_t)k * 2048 + b * 512 + mb + tid];
    if (tid < 32) ss[tid] = ssize[k * 32 + tid];
    __syncthreads();
    const int n4 = (tid & 127) * 4;
    const int m0 = tid >> 7;
    float* ob = out + (((size_t)b * 50 + k) * 512 + mb) * 512;
    for (int mi = m0; mi < 64; mi += 2) {
        const int m = mb + mi;
        const float base = sh[mi];
        floatx4 v;
#pragma unroll
        for (int e = 0; e < 4; ++e) {
            int d = n4 + e - m;
            d = d < -15 ? -15 : (d > 14 ? 14 : d);
            v[e] = base + st[n4 + e] + ss[d + 15];
        }
        __builtin_nontemporal_store(v, (floatx4*)(ob + (size_t)mi * 512 + n4));
    }
}

// ---------------------------------------------------------------------------
extern "C" void kernel_launch(void* const* d_in, const int* in_sizes, int n_in,
                              void* d_out, int out_size, void* d_ws, size_t ws_size,
                              hipStream_t stream)
{
    const float* input_embeds = (const float*)d_in[0];
    const float* Wih_f  = (const float*)d_in[1];
    const float* Whh_f  = (const float*)d_in[2];
    const float* bih_f  = (const float*)d_in[3];
    const float* bhh_f  = (const float*)d_in[4];
    const float* Wih_b  = (const float*)d_in[5];
    const float* Whh_b  = (const float*)d_in[6];
    const float* bih_b  = (const float*)d_in[7];
    const float* bhh_b  = (const float*)d_in[8];
    const float* W_head = (const float*)d_in[9];
    const float* b_head = (const float*)d_in[10];
    const float* W_tail = (const float*)d_in[11];
    const float* b_tail = (const float*)d_in[12];
    const float* emb    = (const float*)d_in[13];
    const float* W      = (const float*)d_in[14];
    float* out = (float*)d_out;

    char* w = (char*)d_ws;
    float* xg     = (float*)w;  w += (size_t)2 * 512 * 4 * 1024 * 4;  // 16 MB
    float* biasc1 = (float*)w;  w += 2048 * 4;
    float* biasc2 = (float*)w;  w += 1024 * 4;
    float* sbias  = (float*)w;  w += 128 * 4;
    float* ssize  = (float*)w;  w += 1600 * 4;
    __hip_bfloat16* wcbf  = (__hip_bfloat16*)w;  w += (size_t)128 * 512 * 2;    // 128 KB
    __hip_bfloat16* wihbf = (__hip_bfloat16*)w;  w += (size_t)2048 * 1024 * 2;  // 4 MB
    __hip_bfloat16* hcat  = (__hip_bfloat16*)w;  w += (size_t)2048 * 512 * 2;   // 2 MB
    // aliased pairs (disjoint lifetimes, stream-ordered):
    //   wc2bf (read by GEMM2) <-> sarrT (written by GEMM3)
    //   abf   (read by GEMM1) <-> ht    (written by GEMM2)
    float* sarrT = (float*)w;
    __hip_bfloat16* wc2bf = (__hip_bfloat16*)w;  w += (size_t)1024 * 512 * 2;   // 1 MB
    __hip_bfloat16* abf   = (__hip_bfloat16*)w;
    __hip_bfloat16* ht    = (__hip_bfloat16*)w;  w += (size_t)2048 * 1024 * 2;  // 4 MB

    hipLaunchKernelGGL(prep_k, dim3(64), dim3(256), 0, stream,
        input_embeds, Wih_f, Wih_b, W_head, W_tail, W, emb,
        bih_f, bhh_f, bih_b, bhh_b, b_head, b_tail,
        ssize, sbias, biasc1, biasc2, abf, wihbf, wc2bf, wcbf);

    // GEMM1: xg = X @ [Wih_f ; Wih_b]^T + bias  (M=2048, N=2048, K=1024), mode 0
    hipLaunchKernelGGL(gemm_bt, dim3(32, 16), dim3(256), 0, stream,
        abf, 1024, 1 << 30, 0,
        wihbf, 1024, biasc1, 1024, 0, xg, (__hip_bfloat16*)nullptr);

    hipLaunchKernelGGL(lstm_k, dim3(2), dim3(1024), 0, stream, Whh_f, Whh_b, xg, hcat);

    // GEMM2: ht = leaky(hcat @ [W_head;W_tail]^T + bias)  (M=2048, N=1024, K=512)
    hipLaunchKernelGGL(gemm_bt, dim3(16, 16), dim3(256), 0, stream,
        hcat, 512, 1 << 30, 0,
        wc2bf, 512, biasc2, 512, 1, (float*)nullptr, ht);

    // GEMM3: sarrT = (ht(head|tail cols) @ wcbf^T + sbias)^T  (M=2048, N=128, K=512)
    hipLaunchKernelGGL(gemm_bt, dim3(2, 16), dim3(256), 0, stream,
        ht, 1024, 64, 512,
        wcbf, 512, sbias, 512, 2, sarrT, (__hip_bfloat16*)nullptr);

    hipLaunchKernelGGL(final_k, dim3(8, 50, 4), dim3(256), 0, stream, sarrT, ssize, out);
}

// Round 6
// 831.641 us; speedup vs baseline: 1.1400x; 1.1400x over previous
//
#include <hip/hip_runtime.h>
#include <hip/hip_bf16.h>
#include <stdint.h>

// Shapes: B=4, N=512, IN=1024, H=256 (MID=512), 4H=1024, OUT_K=50, N_POS=30, SE=64
// out[4][50][512][512] fp32.

typedef float  floatx4 __attribute__((ext_vector_type(4)));
typedef short  short4v __attribute__((ext_vector_type(4)));
typedef short  short8  __attribute__((ext_vector_type(8)));
typedef int    int4v   __attribute__((ext_vector_type(4)));

#define LOG2E_F  1.4426950408889634f
#define TWOLOG2E_F 2.8853900817779268f

__device__ __forceinline__ short f2bf(float f) {
    __hip_bfloat16 h = __float2bfloat16(f);
    return *reinterpret_cast<short*>(&h);
}
__device__ __forceinline__ float fexp2(float x) {
#if __has_builtin(__builtin_amdgcn_exp2f)
    return __builtin_amdgcn_exp2f(x);
#else
    float r; asm("v_exp_f32 %0, %1" : "=v"(r) : "v"(x)); return r;
#endif
}
__device__ __forceinline__ float frcp(float x) {
#if __has_builtin(__builtin_amdgcn_rcpf)
    return __builtin_amdgcn_rcpf(x);
#else
    float r; asm("v_rcp_f32 %0, %1" : "=v"(r) : "v"(x)); return r;
#endif
}
__device__ __forceinline__ int q8i(float x) {
    int q = (int)rintf(x);
    return q > 127 ? 127 : (q < -127 ? -127 : q);
}

// ---------------------------------------------------------------------------
// prep: ssize[50][32] = Ws @ emb^T ; sbias[128]; biasc1[2048]; biasc2[1024];
// bf16 pre-conversions:
//   abf   [2048][1024] = input_embeds            (aliases ht region)
//   wihbf [2048][1024] = [Wih_f ; Wih_b]
//   wc2bf [1024][512]  = [W_head ; W_tail]       (aliases sarrT region)
//   wcbf  [128][512]   = [Wh;0;Wt;0] rows of W
// ---------------------------------------------------------------------------
__global__ __launch_bounds__(256) void prep_k(
    const float* __restrict__ input_embeds,
    const float* __restrict__ Wih_f, const float* __restrict__ Wih_b,
    const float* __restrict__ W_head, const float* __restrict__ W_tail,
    const float* __restrict__ W, const float* __restrict__ emb,
    const float* __restrict__ bih_f, const float* __restrict__ bhh_f,
    const float* __restrict__ bih_b, const float* __restrict__ bhh_b,
    const float* __restrict__ b_head, const float* __restrict__ b_tail,
    float* __restrict__ ssize, float* __restrict__ sbias,
    float* __restrict__ biasc1, float* __restrict__ biasc2,
    __hip_bfloat16* __restrict__ abf, __hip_bfloat16* __restrict__ wihbf,
    __hip_bfloat16* __restrict__ wc2bf, __hip_bfloat16* __restrict__ wcbf)
{
    const int g0 = blockIdx.x * 256 + threadIdx.x;
    const int gs = gridDim.x * 256;

    for (int i4 = g0; i4 < (2048 * 1024) / 4; i4 += gs) {
        floatx4 v = *(const floatx4*)(input_embeds + (size_t)i4 * 4);
        short4v s = { f2bf(v[0]), f2bf(v[1]), f2bf(v[2]), f2bf(v[3]) };
        *(short4v*)(abf + (size_t)i4 * 4) = s;
    }
    for (int i4 = g0; i4 < (2048 * 1024) / 4; i4 += gs) {
        int r = i4 >> 8, c4 = (i4 & 255) * 4;
        const float* src = (r < 1024) ? (Wih_f + (size_t)r * 1024 + c4)
                                      : (Wih_b + (size_t)(r - 1024) * 1024 + c4);
        floatx4 v = *(const floatx4*)src;
        short4v s = { f2bf(v[0]), f2bf(v[1]), f2bf(v[2]), f2bf(v[3]) };
        *(short4v*)(wihbf + (size_t)i4 * 4) = s;
    }
    for (int i4 = g0; i4 < (1024 * 512) / 4; i4 += gs) {
        int r = i4 >> 7, c4 = (i4 & 127) * 4;
        const float* src = (r < 512) ? (W_head + (size_t)r * 512 + c4)
                                     : (W_tail + (size_t)(r - 512) * 512 + c4);
        floatx4 v = *(const floatx4*)src;
        short4v s = { f2bf(v[0]), f2bf(v[1]), f2bf(v[2]), f2bf(v[3]) };
        *(short4v*)(wc2bf + (size_t)i4 * 4) = s;
    }
    for (int i4 = g0; i4 < (128 * 512) / 4; i4 += gs) {
        int r = i4 >> 7, c4 = (i4 & 127) * 4;
        short4v s = {0, 0, 0, 0};
        if (r < 50) {
            const float* p = W + (size_t)r * 1090 + c4;
            s[0] = f2bf(p[0]); s[1] = f2bf(p[1]); s[2] = f2bf(p[2]); s[3] = f2bf(p[3]);
        } else if (r >= 64 && r < 114) {
            const float* p = W + (size_t)(r - 64) * 1090 + 513 + c4;
            s[0] = f2bf(p[0]); s[1] = f2bf(p[1]); s[2] = f2bf(p[2]); s[3] = f2bf(p[3]);
        }
        *(short4v*)(wcbf + (size_t)i4 * 4) = s;
    }

    for (int i = g0; i < 1600; i += gs) {          // ssize [50][32], cols 30,31 = 0
        int k = i >> 5, pp = i & 31;
        float acc = 0.0f;
        if (pp < 30)
            for (int h = 0; h < 64; ++h)
                acc += W[(size_t)k * 1090 + 1026 + h] * emb[pp * 64 + h];
        ssize[i] = acc;
    }
    for (int i = g0; i < 128; i += gs) {
        float v = 0.0f;
        if (i < 50)                    v = W[(size_t)i * 1090 + 512];
        else if (i >= 64 && i < 114)   v = W[(size_t)(i - 64) * 1090 + 1025];
        sbias[i] = v;
    }
    for (int i = g0; i < 2048; i += gs)
        biasc1[i] = (i < 1024) ? (bih_f[i] + bhh_f[i]) : (bih_b[i - 1024] + bhh_b[i - 1024]);
    for (int i = g0; i < 1024; i += gs)
        biasc2[i] = (i < 512) ? b_head[i] : b_tail[i - 512];
}

// ---------------------------------------------------------------------------
// gemm_bt: C[m][n] = sum_k A[m][k] * B[n][k] + bias[n]; A,B bf16.
// Block tile 128x64, 4 waves each 32 (M) x 64 (N). BK=32. MFMA 16x16x32 bf16.
// mode 0: permuted fp32 store into xg[d][t][b][vrow] (vrow = unit*4+gate),
//         PRE-SCALED per gate: i,f,o -> -log2e ; g -> +2*log2e
// mode 1: leaky_relu -> bf16 store, row stride 1024    (GEMM2)
// mode 2: TRANSPOSED fp32 store sarrT[n][m], ld 2048   (GEMM3)
// ---------------------------------------------------------------------------
__global__ __launch_bounds__(256) void gemm_bt(
    const __hip_bfloat16* __restrict__ Abf, int lda,
    int a_split_n, int a_split_off,
    const __hip_bfloat16* __restrict__ Bbf, int ldb,
    const float* __restrict__ bias, int K, int mode,
    float* __restrict__ out0, __hip_bfloat16* __restrict__ out1)
{
    __shared__ __align__(16) short As[128][48];   // stride 48 el = 96 B (conflict pad)
    __shared__ __align__(16) short Bs[64][48];
    const int tid   = threadIdx.x;
    const int nbase = blockIdx.x * 64;
    const int mbase = blockIdx.y * 128;
    const int aoff  = (nbase >= a_split_n) ? a_split_off : 0;
    const int arow = tid >> 1, akq = (tid & 1) * 16;   // A: 128 rows x 32k, 16 el/thread
    const int brow = tid >> 2, bkq = (tid & 3) * 8;    // B: 64 rows x 32k, 8 el/thread
    const int wv = tid >> 6, ln = tid & 63, l15 = ln & 15, quad = ln >> 4;

    floatx4 acc[2][4];
#pragma unroll
    for (int i = 0; i < 2; ++i)
#pragma unroll
        for (int j = 0; j < 4; ++j) acc[i][j] = (floatx4){0.f, 0.f, 0.f, 0.f};

    const unsigned short* A = (const unsigned short*)Abf;
    const unsigned short* B = (const unsigned short*)Bbf;
    const int KI = K >> 5;
    for (int kk = 0; kk < KI; ++kk) {
        const unsigned short* pa = A + (size_t)(mbase + arow) * lda + aoff + kk * 32 + akq;
        short8 sa0 = *(const short8*)pa;
        short8 sa1 = *(const short8*)(pa + 8);
        const unsigned short* pb = B + (size_t)(nbase + brow) * ldb + kk * 32 + bkq;
        short8 sb = *(const short8*)pb;

        __syncthreads();   // previous iter's MFMA reads done
        *(short8*)&As[arow][akq]     = sa0;
        *(short8*)&As[arow][akq + 8] = sa1;
        *(short8*)&Bs[brow][bkq]     = sb;
        __syncthreads();   // staging visible

        short8 a0 = *(const short8*)&As[wv * 32 + l15][quad * 8];
        short8 a1 = *(const short8*)&As[wv * 32 + 16 + l15][quad * 8];
#pragma unroll
        for (int nt = 0; nt < 4; ++nt) {
            short8 bb = *(const short8*)&Bs[nt * 16 + l15][quad * 8];
            acc[0][nt] = __builtin_amdgcn_mfma_f32_16x16x32_bf16(a0, bb, acc[0][nt], 0, 0, 0);
            acc[1][nt] = __builtin_amdgcn_mfma_f32_16x16x32_bf16(a1, bb, acc[1][nt], 0, 0, 0);
        }
    }

#pragma unroll
    for (int mt = 0; mt < 2; ++mt)
#pragma unroll
        for (int nt = 0; nt < 4; ++nt) {
            const int gc = nbase + nt * 16 + l15;
            const float bv = bias[gc];
#pragma unroll
            for (int r = 0; r < 4; ++r) {
                const int gr = mbase + wv * 32 + mt * 16 + quad * 4 + r;
                float v = acc[mt][nt][r] + bv;
                if (mode == 0) {
                    // xg[d][t][b][vrow], vrow = unit*4 + gate (gate = nn>>8, unit = nn&255)
                    const int d = gc >> 10, nn = gc & 1023;
                    const int gate = nn >> 8;
                    const int vrow = ((nn & 255) << 2) | gate;
                    const int t = gr & 511, b = gr >> 9;
                    const float gsc = (gate == 2) ? TWOLOG2E_F : -LOG2E_F;
                    out0[(((size_t)d * 512 + t) * 4 + b) * 1024 + vrow] = v * gsc;
                } else if (mode == 1) {
                    v = v < 0.0f ? 0.01f * v : v;
                    out1[(size_t)gr * 1024 + gc] = __float2bfloat16(v);
                } else {
                    out0[(size_t)gc * 2048 + gr] = v;   // sarrT[n][m]
                }
            }
        }
}

// ---------------------------------------------------------------------------
// lstm_k: 2 blocks (fwd/bwd) x 1024 threads. Whh quantized to per-row i8,
// register-resident A-frags; per-step mfma_i32_16x16x64_i8 (M=1024,N=16,K=256).
// R3-verified structure (522 us). R5 adds only s_setprio(1/0) around the MFMA
// cluster (T5: waves drift across the step -> MFMA-phase waves win arbitration).
// Hot-loop barrier is lgkmcnt-only (global store + xg prefetch in flight).
// ---------------------------------------------------------------------------
__global__ __launch_bounds__(1024) void lstm_k(
    const float* __restrict__ Whh_f, const float* __restrict__ Whh_b,
    const float* __restrict__ xg, __hip_bfloat16* __restrict__ hcat)
{
    const int dir = blockIdx.x;
    const float* Whh = dir ? Whh_b : Whh_f;
    const float* xgd = xg + (size_t)dir * 512 * 4 * 1024;
    __shared__ __align__(16) float sm_lds[1024];
    __shared__ __align__(16) signed char hq[2][4][64][16];  // [parity][kf][slot][16 i8]
    __shared__ __align__(16) int gexch[16][64][4];          // per-wave repack buffer
    const int tid = threadIdx.x;
    const int wv = tid >> 6, ln = tid & 63, l15 = ln & 15, quad = ln >> 4;

    // pass 1: per-vrow max|Whh| (wave-per-row, coalesced)
    for (int v = wv * 64; v < wv * 64 + 64; ++v) {
        const int orig = ((v & 3) << 8) | (v >> 2);   // gate*256 + unit
        floatx4 x = *(const floatx4*)(Whh + (size_t)orig * 256 + ln * 4);
        float m = fmaxf(fmaxf(fabsf(x[0]), fabsf(x[1])), fmaxf(fabsf(x[2]), fabsf(x[3])));
#pragma unroll
        for (int off = 32; off; off >>= 1) m = fmaxf(m, __shfl_xor(m, off, 64));
        if (ln == 0) sm_lds[v] = m;
    }
    for (int i = tid; i < 2 * 4 * 64 * 16 / 4; i += 1024) ((int*)hq)[i] = 0;
    __syncthreads();

    // pass 2: quantize Whh into register A-frags (4 M-tiles x 4 K-frags per wave)
    int4v afrag[4][4];
#pragma unroll
    for (int tt = 0; tt < 4; ++tt) {
        const int vrow = (wv * 4 + tt) * 16 + l15;
        const int orig = ((vrow & 3) << 8) | (vrow >> 2);
        const float sm = sm_lds[vrow];
        const float inv = sm > 1e-30f ? 127.0f / sm : 0.0f;
#pragma unroll
        for (int kf = 0; kf < 4; ++kf) {
            const float* p = Whh + (size_t)orig * 256 + kf * 64 + quad * 16;
            int4v fr;
#pragma unroll
            for (int j = 0; j < 4; ++j) {
                floatx4 w4 = *(const floatx4*)(p + j * 4);
                int b0 = q8i(w4[0] * inv), b1 = q8i(w4[1] * inv);
                int b2 = q8i(w4[2] * inv), b3 = q8i(w4[3] * inv);
                fr[j] = (b0 & 255) | ((b1 & 255) << 8) | ((b2 & 255) << 16) | (b3 << 24);
            }
            afrag[tt][kf] = fr;
        }
    }

    // static per-lane gate-set assignment: unit u_mine, batch (all 64 lanes used)
    const int u_mine = wv * 16 + (ln >> 2);
    const int batch  = ln & 3;
    floatx4 scl;
    {
        const float sc = 1.0f / 16129.0f;   // 1/127^2
        floatx4 s4 = *(const floatx4*)&sm_lds[u_mine * 4];
        scl[0] = s4[0] * (sc * -LOG2E_F);
        scl[1] = s4[1] * (sc * -LOG2E_F);
        scl[2] = s4[2] * (sc *  TWOLOG2E_F);
        scl[3] = s4[3] * (sc * -LOG2E_F);
    }
    // hq write slot for this lane's h value (B-frag layout, verified in R1)
    signed char* hq_w = &hq[0][u_mine >> 6][(((u_mine >> 4) & 3) << 4) + batch][u_mine & 15];
    const int t0 = dir ? 511 : 0;
    const ptrdiff_t xstep = dir ? -4096 : 4096;    // floats per t-step
    const ptrdiff_t hstep = dir ? -512 : 512;      // bf16 elements per t-step
    const float* xp = xgd + (size_t)batch * 1024 + u_mine * 4 + (size_t)t0 * 4096;
    __hip_bfloat16* hc_p = hcat + (size_t)batch * 512 * 512 + dir * 256 + u_mine
                                + (size_t)t0 * 512;

    float c = 0.0f;
    const int4v z4 = {0, 0, 0, 0};   // persistent C=0 operand for kf=0 MFMA
    __syncthreads();

    floatx4 xga = *(const floatx4*)xp;
    floatx4 xgb;

    // One sub-step. P = parity read this step (write P^1). XC = this step's xg
    // regs, XN = regs filled with the prefetch. Trailing barrier drains LDS
    // only (lgkmcnt): hcat global store + xg prefetch stay in flight.
#define LSTM_STEP(P, XC, XN)                                                    \
    {                                                                           \
        xp += xstep;                                                            \
        XN = *(const floatx4*)xp;  /* prefetch; final one strays into the other \
                                      dir's region (valid mem, value unused) */ \
        int4v bb0 = *(const int4v*)&hq[P][0][ln][0];                            \
        int4v bb1 = *(const int4v*)&hq[P][1][ln][0];                            \
        int4v bb2 = *(const int4v*)&hq[P][2][ln][0];                            \
        int4v bb3 = *(const int4v*)&hq[P][3][ln][0];                            \
        int4v acc[4];                                                           \
        __builtin_amdgcn_s_setprio(1);                                          \
        _Pragma("unroll")                                                       \
        for (int tt = 0; tt < 4; ++tt) {                                        \
            int4v t0v = __builtin_amdgcn_mfma_i32_16x16x64_i8(                  \
                afrag[tt][0], bb0, z4, 0, 0, 0);                                \
            t0v = __builtin_amdgcn_mfma_i32_16x16x64_i8(                        \
                afrag[tt][1], bb1, t0v, 0, 0, 0);                               \
            t0v = __builtin_amdgcn_mfma_i32_16x16x64_i8(                        \
                afrag[tt][2], bb2, t0v, 0, 0, 0);                               \
            acc[tt] = __builtin_amdgcn_mfma_i32_16x16x64_i8(                    \
                afrag[tt][3], bb3, t0v, 0, 0, 0);                               \
        }                                                                       \
        __builtin_amdgcn_s_setprio(0);                                          \
        if (l15 < 4) {                                                          \
            _Pragma("unroll")                                                   \
            for (int tt = 0; tt < 4; ++tt)                                      \
                *(int4v*)&gexch[wv][(tt * 4 + quad) * 4 + l15][0] = acc[tt];    \
        }                                                                       \
        int4v g = *(const int4v*)&gexch[wv][ln][0];                             \
        float gi = fmaf((float)g[0], scl[0], XC[0]);                            \
        float gf = fmaf((float)g[1], scl[1], XC[1]);                            \
        float gg = fmaf((float)g[2], scl[2], XC[2]);                            \
        float go = fmaf((float)g[3], scl[3], XC[3]);                            \
        float iv = frcp(1.0f + fexp2(gi));           /* sigmoid (pre * -log2e) */\
        float fv = frcp(1.0f + fexp2(gf));                                      \
        float tg = fmaf(-2.0f, frcp(1.0f + fexp2(gg)), 1.0f); /* tanh */        \
        float ov = frcp(1.0f + fexp2(go));                                      \
        c = fmaf(fv, c, iv * tg);                                               \
        float tc = fmaf(-2.0f, frcp(1.0f + fexp2(c * TWOLOG2E_F)), 1.0f);       \
        float h = ov * tc;                                                      \
        *hc_p = __float2bfloat16(h);                                            \
        hq_w[(P) ? 0 : 4096] = (signed char)(int)rintf(h * 127.0f); /* |h|<1 */ \
        hc_p += hstep;                                                          \
        asm volatile("s_waitcnt lgkmcnt(0)" ::: "memory");                      \
        __builtin_amdgcn_s_barrier();                                           \
        __builtin_amdgcn_sched_barrier(0);                                      \
        asm volatile("" ::: "memory");                                          \
    }

    for (int s = 0; s < 512; s += 2) {
        LSTM_STEP(0, xga, xgb)
        LSTM_STEP(1, xgb, xga)
    }
#undef LSTM_STEP
}

// ---------------------------------------------------------------------------
// final: out[b][k][m][n] = s_head[b,m,k] + s_tail[b,n,k] + S[k][clamp(n-m)]
// sarrT is transposed: sarrT[col 0..127][m 0..2047] -> contiguous loads here.
// ---------------------------------------------------------------------------
__global__ __launch_bounds__(256) void final_k(
    const float* __restrict__ sarrT, const float* __restrict__ ssize,
    float* __restrict__ out)
{
    const int mb = blockIdx.x * 64;
    const int k  = blockIdx.y;
    const int b  = blockIdx.z;
    __shared__ float st[512];
    __shared__ float sh[64];
    __shared__ float ss[32];
    const int tid = threadIdx.x;
    for (int n = tid; n < 512; n += 256)
        st[n] = sarrT[(size_t)(64 + k) * 2048 + b * 512 + n];
    if (tid < 64) sh[tid] = sarrT[(size_t)k * 2048 + b * 512 + mb + tid];
    if (tid < 32) ss[tid] = ssize[k * 32 + tid];
    __syncthreads();
    const int n4 = (tid & 127) * 4;
    const int m0 = tid >> 7;
    float* ob = out + (((size_t)b * 50 + k) * 512 + mb) * 512;
    for (int mi = m0; mi < 64; mi += 2) {
        const int m = mb + mi;
        const float base = sh[mi];
        floatx4 v;
#pragma unroll
        for (int e = 0; e < 4; ++e) {
            int d = n4 + e - m;
            d = d < -15 ? -15 : (d > 14 ? 14 : d);
            v[e] = base + st[n4 + e] + ss[d + 15];
        }
        __builtin_nontemporal_store(v, (floatx4*)(ob + (size_t)mi * 512 + n4));
    }
}

// ---------------------------------------------------------------------------
extern "C" void kernel_launch(void* const* d_in, const int* in_sizes, int n_in,
                              void* d_out, int out_size, void* d_ws, size_t ws_size,
                              hipStream_t stream)
{
    const float* input_embeds = (const float*)d_in[0];
    const float* Wih_f  = (const float*)d_in[1];
    const float* Whh_f  = (const float*)d_in[2];
    const float* bih_f  = (const float*)d_in[3];
    const float* bhh_f  = (const float*)d_in[4];
    const float* Wih_b  = (const float*)d_in[5];
    const float* Whh_b  = (const float*)d_in[6];
    const float* bih_b  = (const float*)d_in[7];
    const float* bhh_b  = (const float*)d_in[8];
    const float* W_head = (const float*)d_in[9];
    const float* b_head = (const float*)d_in[10];
    const float* W_tail = (const float*)d_in[11];
    const float* b_tail = (const float*)d_in[12];
    const float* emb    = (const float*)d_in[13];
    const float* W      = (const float*)d_in[14];
    float* out = (float*)d_out;

    char* w = (char*)d_ws;
    float* xg     = (float*)w;  w += (size_t)2 * 512 * 4 * 1024 * 4;  // 16 MB
    float* biasc1 = (float*)w;  w += 2048 * 4;
    float* biasc2 = (float*)w;  w += 1024 * 4;
    float* sbias  = (float*)w;  w += 128 * 4;
    float* ssize  = (float*)w;  w += 1600 * 4;
    __hip_bfloat16* wcbf  = (__hip_bfloat16*)w;  w += (size_t)128 * 512 * 2;    // 128 KB
    __hip_bfloat16* wihbf = (__hip_bfloat16*)w;  w += (size_t)2048 * 1024 * 2;  // 4 MB
    __hip_bfloat16* hcat  = (__hip_bfloat16*)w;  w += (size_t)2048 * 512 * 2;   // 2 MB
    // aliased pairs (disjoint lifetimes, stream-ordered):
    //   wc2bf (read by GEMM2) <-> sarrT (written by GEMM3)
    //   abf   (read by GEMM1) <-> ht    (written by GEMM2)
    float* sarrT = (float*)w;
    __hip_bfloat16* wc2bf = (__hip_bfloat16*)w;  w += (size_t)1024 * 512 * 2;   // 1 MB
    __hip_bfloat16* abf   = (__hip_bfloat16*)w;
    __hip_bfloat16* ht    = (__hip_bfloat16*)w;  w += (size_t)2048 * 1024 * 2;  // 4 MB

    hipLaunchKernelGGL(prep_k, dim3(64), dim3(256), 0, stream,
        input_embeds, Wih_f, Wih_b, W_head, W_tail, W, emb,
        bih_f, bhh_f, bih_b, bhh_b, b_head, b_tail,
        ssize, sbias, biasc1, biasc2, abf, wihbf, wc2bf, wcbf);

    // GEMM1: xg = X @ [Wih_f ; Wih_b]^T + bias  (M=2048, N=2048, K=1024), mode 0
    hipLaunchKernelGGL(gemm_bt, dim3(32, 16), dim3(256), 0, stream,
        abf, 1024, 1 << 30, 0,
        wihbf, 1024, biasc1, 1024, 0, xg, (__hip_bfloat16*)nullptr);

    hipLaunchKernelGGL(lstm_k, dim3(2), dim3(1024), 0, stream, Whh_f, Whh_b, xg, hcat);

    // GEMM2: ht = leaky(hcat @ [W_head;W_tail]^T + bias)  (M=2048, N=1024, K=512)
    hipLaunchKernelGGL(gemm_bt, dim3(16, 16), dim3(256), 0, stream,
        hcat, 512, 1 << 30, 0,
        wc2bf, 512, biasc2, 512, 1, (float*)nullptr, ht);

    // GEMM3: sarrT = (ht(head|tail cols) @ wcbf^T + sbias)^T  (M=2048, N=128, K=512)
    hipLaunchKernelGGL(gemm_bt, dim3(2, 16), dim3(256), 0, stream,
        ht, 1024, 64, 512,
        wcbf, 512, sbias, 512, 2, sarrT, (__hip_bfloat16*)nullptr);

    hipLaunchKernelGGL(final_k, dim3(8, 50, 4), dim3(256), 0, stream, sarrT, ssize, out);
}